// Round 1
// 651.455 us; speedup vs baseline: 1.0026x; 1.0026x over previous
//
#include <hip/hip_runtime.h>
#include <hip/hip_bf16.h>
#include <math.h>

typedef __bf16 bf16_8 __attribute__((ext_vector_type(8)));
typedef __bf16 bf16_4 __attribute__((ext_vector_type(4)));
typedef float  f32x4  __attribute__((ext_vector_type(4)));

static __device__ __forceinline__ float sigmoidf_(float x){ return 1.0f/(1.0f + expf(-x)); }

#define BB 128
#define HH 1024
#define SS 512
#define VV 32000

// ---------- workspace layout (bytes) ----------
#define OFF_A0    0u            // bf16 [128][2048]
#define OFF_A1    524288u       // bf16 [128][2048]
#define OFF_ALOG  1048576u      // bf16 [128][1024]
#define OFF_AH    1310720u      // bf16 [128][1024]
#define OFF_AM    1572864u
#define OFF_AL    1835008u
#define OFF_WAT   2097152u      // f32 [1024][1024]
#define OFF_Q     6291456u      // f32 [128][1024]
#define OFF_Z     6815744u      // f32 [128][1024]
#define OFF_PT    7340032u      // f32 [128]
#define OFF_SI    7340544u      // i32 [128]
#define OFF_SC    7341056u      // f32 [128][132]
#define OFF_G0P   7408640u      // f32 [4][128][4096] K-split partials, layer 0 (8 MB)
#define OFF_G1P   15797248u     // f32 [4][128][4096] K-split partials, layer 1 (8 MB)
#define OFF_PMAX  24185856u     // f32 [250][128]
#define OFF_PSUM  24313856u     // f32 [250][128]

// ---------- fused: W_a transpose + emb gather + h split + z/q init ----------
// blocks [0,1024):   W_a 32x32 transpose tiles
// blocks [1024,1152): per-b emb gather -> A0, h_top 3-way bf16 split, z=b_pt, q=0
__global__ void k_prep_all(const float* __restrict__ W_a, float* __restrict__ WaT,
                           const int* __restrict__ ids, const float* __restrict__ emb,
                           const float* __restrict__ h, const float* __restrict__ b_pt,
                           __bf16* __restrict__ A0, __bf16* __restrict__ Ah,
                           __bf16* __restrict__ Am, __bf16* __restrict__ Al,
                           float* __restrict__ z, float* __restrict__ q){
  __shared__ float tsm[32][33];
  int blk = blockIdx.x, t = threadIdx.x;
  if (blk < 1024){
    int kt = blk & 31, nt = blk >> 5;
    int c = t & 31, r0 = t >> 5;
    #pragma unroll
    for (int i = 0; i < 4; ++i){
      int r = r0 + 8*i;
      tsm[r][c] = W_a[(size_t)(kt*32 + r)*HH + nt*32 + c];
    }
    __syncthreads();
    #pragma unroll
    for (int i = 0; i < 4; ++i){
      int r = r0 + 8*i;
      WaT[(size_t)(nt*32 + r)*HH + kt*32 + c] = tsm[c][r];
    }
  } else {
    int b = blk - 1024, c = t*4;
    int tok = ids[b];
    f32x4 e = *(const f32x4*)(emb + (size_t)tok*HH + c);
    bf16_4 e4;
    #pragma unroll
    for (int i=0;i<4;i++) e4[i] = (__bf16)e[i];
    *(bf16_4*)(A0 + (size_t)b*2048 + c) = e4;
    f32x4 x = *(const f32x4*)(h + (size_t)BB*HH + (size_t)b*HH + c); // h[1]
    bf16_4 hi4, mi4, lo4;
    #pragma unroll
    for (int i=0;i<4;i++){
      float v = x[i];
      __bf16 bh = (__bf16)v; float r1 = v - (float)bh;
      __bf16 bm = (__bf16)r1; float r2 = r1 - (float)bm;
      hi4[i]=bh; mi4[i]=bm; lo4[i]=(__bf16)r2;
    }
    *(bf16_4*)(Ah + (size_t)b*HH + c) = hi4;
    *(bf16_4*)(Am + (size_t)b*HH + c) = mi4;
    *(bf16_4*)(Al + (size_t)b*HH + c) = lo4;
    *(f32x4*)(z + (size_t)b*HH + c) = *(const f32x4*)(b_pt + c);
    *(f32x4*)(q + (size_t)b*HH + c) = f32x4{0.f,0.f,0.f,0.f};
  }
}

// ---------- small precision-split GEMM body (BK=32), atomic K-split epilogue ----------
template<int PREC>
__device__ __forceinline__ void gemm_small(
    char* smem,
    const __bf16* __restrict__ Ah, const __bf16* __restrict__ Am, const __bf16* __restrict__ Al,
    int lda, const float* __restrict__ B1, int K,
    float* __restrict__ C, int N, int xblk, int ysplit)
{
  constexpr int NS   = PREC;
  constexpr int BK   = 32;
  constexpr int KG   = BK/8;          // 4
  constexpr int TILE = 128*BK*2;      // 8192
  constexpr int UPT  = (128*KG)/256;  // 2
  char* sA = smem;
  char* sB = smem + NS*TILE;

  const int t = threadIdx.x;
  const int lane = t & 63, wave = t >> 6;
  const int wm = wave >> 1, wn = wave & 1;
  const int quad = lane >> 4, ln = lane & 15;
  const int nblock = xblk * 128;
  const int kchunk = K / ysplit;
  const int kstart = blockIdx.y * kchunk;
  const int kend = kstart + kchunk;

  f32x4 acc[4][4];
  #pragma unroll
  for (int i=0;i<4;i++)
    #pragma unroll
    for (int j=0;j<4;j++) acc[i][j] = f32x4{0.f,0.f,0.f,0.f};

  for (int k0 = kstart; k0 < kend; k0 += BK){
    #pragma unroll
    for (int i = 0; i < UPT; ++i){
      int u = t + 256*i;
      int row = u / KG, kg = u % KG;
      int sl = row*(BK*2) + (((kg ^ (row & (KG-1)))) << 4);
      *(uint4*)(sA + sl) = *(const uint4*)(Ah + (size_t)row*lda + k0 + kg*8);
      if constexpr (PREC >= 2)
        *(uint4*)(sA + TILE + sl) = *(const uint4*)(Am + (size_t)row*lda + k0 + kg*8);
      if constexpr (PREC >= 3)
        *(uint4*)(sA + 2*TILE + sl) = *(const uint4*)(Al + (size_t)row*lda + k0 + kg*8);
      int ng = nblock + row;
      const float* src = B1 + (size_t)ng*K + k0 + kg*8;
      f32x4 x0 = *(const f32x4*)(src);
      f32x4 x1 = *(const f32x4*)(src + 4);
      bf16_8 hi, mi, lo;
      #pragma unroll
      for (int qv=0;qv<8;qv++){
        float v = (qv<4) ? x0[qv] : x1[qv-4];
        __bf16 bh = (__bf16)v;
        hi[qv] = bh;
        float r1 = v - (float)bh;
        __bf16 bm = (__bf16)r1;
        mi[qv] = bm;
        lo[qv] = (__bf16)(r1 - (float)bm);
      }
      *(bf16_8*)(sB + sl) = hi;
      if constexpr (PREC >= 2) *(bf16_8*)(sB + TILE + sl) = mi;
      if constexpr (PREC >= 3) *(bf16_8*)(sB + 2*TILE + sl) = lo;
    }
    __syncthreads();
    {
      bf16_8 af[NS][4], bfr[NS][4];
      #pragma unroll
      for (int mt=0; mt<4; ++mt){
        int row = wm*64 + mt*16 + ln;
        int kg = quad;
        int sl = row*(BK*2) + (((kg ^ (row & (KG-1)))) << 4);
        #pragma unroll
        for (int s=0;s<NS;s++) af[s][mt] = *(const bf16_8*)(sA + s*TILE + sl);
      }
      #pragma unroll
      for (int nt=0; nt<4; ++nt){
        int row = wn*64 + nt*16 + ln;
        int kg = quad;
        int sl = row*(BK*2) + (((kg ^ (row & (KG-1)))) << 4);
        #pragma unroll
        for (int s=0;s<NS;s++) bfr[s][nt] = *(const bf16_8*)(sB + s*TILE + sl);
      }
      #pragma unroll
      for (int mt=0; mt<4; ++mt)
        #pragma unroll
        for (int nt=0; nt<4; ++nt){
          acc[mt][nt] = __builtin_amdgcn_mfma_f32_16x16x32_bf16(af[0][mt], bfr[0][nt], acc[mt][nt], 0,0,0);
          if constexpr (PREC >= 2){
            acc[mt][nt] = __builtin_amdgcn_mfma_f32_16x16x32_bf16(af[0][mt], bfr[1][nt], acc[mt][nt], 0,0,0);
            acc[mt][nt] = __builtin_amdgcn_mfma_f32_16x16x32_bf16(af[1][mt], bfr[0][nt], acc[mt][nt], 0,0,0);
          }
          if constexpr (PREC >= 3){
            acc[mt][nt] = __builtin_amdgcn_mfma_f32_16x16x32_bf16(af[0][mt], bfr[2][nt], acc[mt][nt], 0,0,0);
            acc[mt][nt] = __builtin_amdgcn_mfma_f32_16x16x32_bf16(af[1][mt], bfr[1][nt], acc[mt][nt], 0,0,0);
            acc[mt][nt] = __builtin_amdgcn_mfma_f32_16x16x32_bf16(af[2][mt], bfr[0][nt], acc[mt][nt], 0,0,0);
          }
        }
    }
    __syncthreads();
  }

  #pragma unroll
  for (int nt=0; nt<4; ++nt){
    int n = nblock + wn*64 + nt*16 + ln;
    #pragma unroll
    for (int mt=0; mt<4; ++mt){
      int m0 = wm*64 + mt*16 + quad*4;
      #pragma unroll
      for (int r=0;r<4;++r)
        atomicAdd(C + (size_t)(m0 + r)*N + n, acc[mt][nt][r]);
    }
  }
}

// ---------- fused q-GEMM (PREC=2) || z-GEMM (PREC=3), one launch ----------
__global__ __launch_bounds__(256) void k_qz(
    const __bf16* __restrict__ Ah, const __bf16* __restrict__ Am, const __bf16* __restrict__ Al,
    const float* __restrict__ WaT, const float* __restrict__ Wpt,
    float* __restrict__ q, float* __restrict__ z)
{
  __shared__ __align__(16) char smem[49152];
  if (blockIdx.x < 8)
    gemm_small<2>(smem, Ah, Am, nullptr, 1024, WaT, 1024, q, 1024, blockIdx.x, 4);
  else
    gemm_small<3>(smem, Ah, Am, Al, 1024, Wpt, 1024, z, 1024, blockIdx.x - 8, 4);
}

// ---------- MFMA GEMM: C[128,N] = A[128,K] * B^T (PREC=1 pipelined path) ----------
// EPI: 2 = logits (store C + bias, emit per-block (max,sumexp) partials)
//      4 = K-split partial store: C + blockIdx.y*128*N, no bias
template<int PREC, int EPI>
__global__ __launch_bounds__(256) void k_gemm(
    const __bf16* __restrict__ Ah, const __bf16* __restrict__ Am, const __bf16* __restrict__ Al,
    int lda,
    const float* __restrict__ B1, const float* __restrict__ B2, int K1, int K2,
    const float* __restrict__ bias,
    float* __restrict__ C, int N,
    float* __restrict__ Pmax, float* __restrict__ Psum)
{
  constexpr int BK  = 64;
  constexpr int KG  = BK/8;
  constexpr int TILE = 128*BK*2;
  constexpr int UPT = (128*KG)/256;
  __shared__ __align__(16) char smem[2*TILE];
  char* sA = smem;
  char* sB = smem + TILE;

  const int t = threadIdx.x;
  const int lane = t & 63, wave = t >> 6;
  const int wm = wave >> 1, wn = wave & 1;
  const int quad = lane >> 4, ln = lane & 15;
  const int nblock = blockIdx.x * 128;
  const int K = K1 + K2;
  const int kchunk = K / gridDim.y;
  const int kstart = blockIdx.y * kchunk;
  const int kend = kstart + kchunk;

  f32x4 acc[4][4];
  #pragma unroll
  for (int i=0;i<4;i++)
    #pragma unroll
    for (int j=0;j<4;j++) acc[i][j] = f32x4{0.f,0.f,0.f,0.f};

  // software-pipelined: global loads for tile k+1 in flight during MFMA on tile k
  uint4 aR[UPT]; f32x4 bR[UPT][2];
  auto issue = [&](int k0){
    #pragma unroll
    for (int i=0;i<UPT;++i){
      int u = t + 256*i, row = u/KG, kg = u%KG;
      aR[i] = *(const uint4*)(Ah + (size_t)row*lda + k0 + kg*8);
      int ng = nblock + row;
      const float* src = (k0 < K1) ? (B1 + (size_t)ng*K1 + k0 + kg*8)
                                   : (B2 + (size_t)ng*K2 + (k0 - K1) + kg*8);
      bR[i][0] = *(const f32x4*)(src);
      bR[i][1] = *(const f32x4*)(src + 4);
    }
  };
  issue(kstart);
  for (int k0 = kstart; k0 < kend; k0 += BK){
    __syncthreads();
    #pragma unroll
    for (int i=0;i<UPT;++i){
      int u = t + 256*i, row = u/KG, kg = u%KG;
      int sl = row*(BK*2) + (((kg ^ (row & (KG-1)))) << 4);
      *(uint4*)(sA + sl) = aR[i];
      bf16_8 hi;
      #pragma unroll
      for (int qv=0;qv<8;++qv) hi[qv] = (__bf16)((qv<4) ? bR[i][0][qv] : bR[i][1][qv-4]);
      *(bf16_8*)(sB + sl) = hi;
    }
    __syncthreads();
    if (k0 + BK < kend) issue(k0 + BK);
    #pragma unroll
    for (int ks = 0; ks < BK/32; ++ks){
      bf16_8 af[4], bfr[4];
      #pragma unroll
      for (int mt=0; mt<4; ++mt){
        int row = wm*64 + mt*16 + ln;
        int kg = ks*4 + quad;
        int sl = row*(BK*2) + (((kg ^ (row & (KG-1)))) << 4);
        af[mt] = *(const bf16_8*)(sA + sl);
      }
      #pragma unroll
      for (int nt=0; nt<4; ++nt){
        int row = wn*64 + nt*16 + ln;
        int kg = ks*4 + quad;
        int sl = row*(BK*2) + (((kg ^ (row & (KG-1)))) << 4);
        bfr[nt] = *(const bf16_8*)(sB + sl);
      }
      #pragma unroll
      for (int mt=0; mt<4; ++mt)
        #pragma unroll
        for (int nt=0; nt<4; ++nt)
          acc[mt][nt] = __builtin_amdgcn_mfma_f32_16x16x32_bf16(af[mt], bfr[nt], acc[mt][nt], 0,0,0);
    }
  }

  // ---- epilogues ----
  if constexpr (EPI == 4){
    float* Cp = C + (size_t)blockIdx.y * 128 * N;
    #pragma unroll
    for (int nt=0; nt<4; ++nt){
      int n = nblock + wn*64 + nt*16 + ln;
      #pragma unroll
      for (int mt=0; mt<4; ++mt){
        int m0 = wm*64 + mt*16 + quad*4;
        #pragma unroll
        for (int r=0;r<4;++r)
          Cp[(size_t)(m0 + r)*N + n] = acc[mt][nt][r];
      }
    }
  } else if constexpr (EPI == 2){
    __syncthreads();                         // LDS reuse for reductions
    float* redm = (float*)smem;              // [2][128]
    float* reds = (float*)smem + 256;        // [2][128]
    float rmax[16];
    #pragma unroll
    for (int mt=0; mt<4; ++mt)
      #pragma unroll
      for (int r=0;r<4;++r){
        float m4 = -1e30f;
        #pragma unroll
        for (int nt=0;nt<4;++nt){
          int n = nblock + wn*64 + nt*16 + ln;
          m4 = fmaxf(m4, acc[mt][nt][r] + bias[n]);
        }
        #pragma unroll
        for (int m=1;m<16;m<<=1) m4 = fmaxf(m4, __shfl_xor(m4, m));
        rmax[mt*4+r] = m4;
      }
    if (ln == 0){
      #pragma unroll
      for (int mt=0;mt<4;++mt)
        #pragma unroll
        for (int r=0;r<4;++r)
          redm[wn*128 + wm*64 + mt*16 + quad*4 + r] = rmax[mt*4+r];
    }
    __syncthreads();
    #pragma unroll
    for (int mt=0; mt<4; ++mt)
      #pragma unroll
      for (int r=0;r<4;++r){
        int row = wm*64 + mt*16 + quad*4 + r;
        float M = fmaxf(redm[row], redm[128 + row]);
        float s4 = 0.f;
        #pragma unroll
        for (int nt=0;nt<4;++nt){
          int n = nblock + wn*64 + nt*16 + ln;
          float v = acc[mt][nt][r] + bias[n];
          C[(size_t)row*N + n] = v;
          s4 += expf(v - M);
        }
        #pragma unroll
        for (int m=1;m<16;m<<=1) s4 += __shfl_xor(s4, m);
        if (ln == 0) reds[wn*128 + row] = s4;
      }
    __syncthreads();
    if (wn == 0 && ln == 0){
      #pragma unroll
      for (int mt=0;mt<4;++mt)
        #pragma unroll
        for (int r=0;r<4;++r){
          int row = wm*64 + mt*16 + quad*4 + r;
          float M = fmaxf(redm[row], redm[128 + row]);
          Pmax[(size_t)blockIdx.x*128 + row] = M;
          Psum[(size_t)blockIdx.x*128 + row] = reds[row] + reds[128 + row];
        }
    }
  }
}

// ---------- scores with fused p_t/s computation (replaces k_s2) ----------
__global__ __launch_bounds__(256) void k_scores(
    const float* __restrict__ z, const float* __restrict__ v_pt, const float* __restrict__ b_v,
    const float* __restrict__ q, const float* __restrict__ h_s,
    const float* __restrict__ b_a,
    float* __restrict__ sc, float* __restrict__ p_t, int* __restrict__ s_i,
    float* __restrict__ out_s)
{
  __shared__ float red[4];
  __shared__ float sh[2];   // [0]=p_t, [1]=s (float)
  int b = blockIdx.x, t = threadIdx.x;
  // --- p_t prologue (identical FP ops in every block -> deterministic) ---
  {
    f32x4 zv = *(const f32x4*)(z + (size_t)b*HH + t*4);
    f32x4 vv = *(const f32x4*)(v_pt + t*4);
    float ps = tanhf(zv[0])*vv[0] + tanhf(zv[1])*vv[1] + tanhf(zv[2])*vv[2] + tanhf(zv[3])*vv[3];
    #pragma unroll
    for (int m=1;m<64;m<<=1) ps += __shfl_xor(ps, m);
    if ((t&63)==0) red[t>>6] = ps;
    __syncthreads();
    if (t == 0){
      float tot = red[0]+red[1]+red[2]+red[3] + b_v[0];
      float p = (float)SS * sigmoidf_(tot);
      float sf = rintf(p);
      sf = fminf(fmaxf(sf, 64.0f), 447.0f);
      sh[0] = p; sh[1] = sf;
      if (blockIdx.y == 0){ p_t[b] = p; s_i[b] = (int)sf; out_s[b] = sf; }
    }
    __syncthreads();
  }
  int si = (int)sh[1];
  // --- bilinear score for this wave's window position ---
  int jj = blockIdx.y*4 + (t >> 6);
  if (jj >= 129) return;
  int lane = t & 63;
  int pos = si - 64 + jj;
  const float* row = h_s + ((size_t)pos*BB + b)*HH;
  const float* qb  = q + (size_t)b*HH;
  f32x4 a = f32x4{0.f,0.f,0.f,0.f};
  #pragma unroll
  for (int c = lane*4; c < HH; c += 256){
    f32x4 r4 = *(const f32x4*)(row + c);
    f32x4 q4 = *(const f32x4*)(qb + c);
    a += r4*q4;
  }
  float sdot = a[0]+a[1]+a[2]+a[3];
  #pragma unroll
  for (int m=1;m<64;m<<=1) sdot += __shfl_xor(sdot, m);
  if (lane == 0) sc[b*132 + jj] = sdot + b_a[0];
}

// ---------- context with fused softmax*gauss; 2 blocks per b (H halves) ----------
__global__ __launch_bounds__(256) void k_context(
    const float* __restrict__ sc, const int* __restrict__ s_i, const float* __restrict__ p_t,
    const float* __restrict__ h_s, const float* __restrict__ h,
    float* __restrict__ ctx_out, __bf16* __restrict__ A0, __bf16* __restrict__ A1){
  __shared__ float sat[132];
  __shared__ float sctx[4][512];
  __shared__ int spos;
  int bb = blockIdx.x;
  int b = bb >> 1, half = bb & 1;
  int t = threadIdx.x, w = t >> 6, l = t & 63;
  if (w == 0){
    const float* scb = sc + b*132;
    float mx = -1e30f;
    for (int j=l; j<129; j+=64) mx = fmaxf(mx, scb[j]);
    #pragma unroll
    for (int m=1;m<64;m<<=1) mx = fmaxf(mx, __shfl_xor(mx, m));
    float sum = 0.f;
    for (int j=l; j<129; j+=64) sum += expf(scb[j] - mx);
    #pragma unroll
    for (int m=1;m<64;m<<=1) sum += __shfl_xor(sum, m);
    float inv = 1.0f/sum;
    float pt = p_t[b];
    int si = s_i[b];
    if (l == 0) spos = si - 64;
    float s0 = (float)(si - 64);
    for (int j=l; j<129; j+=64){
      float e = expf(scb[j]-mx)*inv;
      float d = (s0 + (float)j) - pt;
      sat[j] = e * expf(-(d*d) * (1.0f/2048.0f));
    }
  }
  __syncthreads();
  int pos0 = spos;
  int jstart = (w == 0) ? 0 : (33 + 32*(w-1));
  int jcnt   = (w == 0) ? 33 : 32;
  const float* base = h_s + ((size_t)pos0*BB + b)*HH + half*512;
  f32x4 acc0 = f32x4{0.f,0.f,0.f,0.f};
  f32x4 acc1 = f32x4{0.f,0.f,0.f,0.f};
  for (int j = jstart; j < jstart + jcnt; ++j){
    const float* row = base + (size_t)j*BB*HH;
    float aj = sat[j];
    acc0 += *(const f32x4*)(row + l*4) * aj;
    acc1 += *(const f32x4*)(row + 256 + l*4) * aj;
  }
  *(f32x4*)(&sctx[w][l*4])       = acc0;
  *(f32x4*)(&sctx[w][256 + l*4]) = acc1;
  __syncthreads();
  if (t < 128){
    int c = t*4;
    f32x4 v = *(f32x4*)(&sctx[0][c]) + *(f32x4*)(&sctx[1][c])
            + *(f32x4*)(&sctx[2][c]) + *(f32x4*)(&sctx[3][c]);
    int gc = half*512 + c;
    *(f32x4*)(ctx_out + (size_t)b*HH + gc) = v;
    f32x4 h0 = *(const f32x4*)(h + (size_t)b*HH + gc) + v;
    f32x4 h1 = *(const f32x4*)(h + (size_t)BB*HH + (size_t)b*HH + gc) + v;
    bf16_4 v0, v1;
    #pragma unroll
    for (int i=0;i<4;i++){ v0[i]=(__bf16)h0[i]; v1[i]=(__bf16)h1[i]; }
    *(bf16_4*)(A0 + (size_t)b*2048 + 1024 + gc) = v0;
    *(bf16_4*)(A1 + (size_t)b*2048 + 1024 + gc) = v1;
  }
}

// ---------- LSTM cell: sums 4 K-split partials + biases (no atomics upstream) ----------
__global__ void k_cell(const float* __restrict__ part,
                       const float* __restrict__ bih, const float* __restrict__ bhh,
                       const float* __restrict__ c_in,
                       float* __restrict__ h_out, float* __restrict__ c_out,
                       __bf16* __restrict__ Anext, int strideNext){
  int g = blockIdx.x*256 + threadIdx.x;
  int b = g >> 10, hc = g & 1023;
  float ig = bih[hc]        + bhh[hc];
  float fg = bih[1024 + hc] + bhh[1024 + hc];
  float gg = bih[2048 + hc] + bhh[2048 + hc];
  float og = bih[3072 + hc] + bhh[3072 + hc];
  #pragma unroll
  for (int y = 0; y < 4; ++y){
    const float* gb = part + ((size_t)y*BB + b)*4096;
    ig += gb[hc]; fg += gb[1024+hc]; gg += gb[2048+hc]; og += gb[3072+hc];
  }
  float cn = sigmoidf_(fg)*c_in[g] + sigmoidf_(ig)*tanhf(gg);
  float hn = sigmoidf_(og)*tanhf(cn);
  c_out[g] = cn; h_out[g] = hn;
  Anext[(size_t)b*strideNext + hc] = (__bf16)hn;
}

// ---------- fused lse-reduce + subtract ----------
__global__ void k_lsesub(const float* __restrict__ Pmax, const float* __restrict__ Psum,
                         float* __restrict__ out){
  int b = blockIdx.y, l = threadIdx.x;   // 64 threads
  float M = -1e30f;
  for (int i=l; i<250; i+=64) M = fmaxf(M, Pmax[(size_t)i*128 + b]);
  #pragma unroll
  for (int m=1;m<64;m<<=1) M = fmaxf(M, __shfl_xor(M, m));
  float s = 0.f;
  for (int i=l; i<250; i+=64) s += Psum[(size_t)i*128 + b] * expf(Pmax[(size_t)i*128 + b] - M);
  #pragma unroll
  for (int m=1;m<64;m<<=1) s += __shfl_xor(s, m);
  float L = M + logf(s);
  int i = blockIdx.x*256 + l*4;
  f32x4 v = *(f32x4*)(out + (size_t)b*VV + i);
  v[0]-=L; v[1]-=L; v[2]-=L; v[3]-=L;
  *(f32x4*)(out + (size_t)b*VV + i) = v;
}

// ---------- launch ----------
extern "C" void kernel_launch(void* const* d_in, const int* in_sizes, int n_in,
                              void* d_out, int out_size, void* d_ws, size_t ws_size,
                              hipStream_t stream){
  const int*   ids   = (const int*)d_in[0];
  const float* h     = (const float*)d_in[1];
  const float* c     = (const float*)d_in[2];
  const float* h_s   = (const float*)d_in[3];
  const float* emb   = (const float*)d_in[4];
  const float* W_pt  = (const float*)d_in[5];
  const float* b_pt  = (const float*)d_in[6];
  const float* v_pt  = (const float*)d_in[7];
  const float* b_v   = (const float*)d_in[8];
  const float* W_a   = (const float*)d_in[9];
  const float* b_a   = (const float*)d_in[10];
  const float* W_ih  = (const float*)d_in[11];
  const float* W_hh  = (const float*)d_in[12];
  const float* b_ih  = (const float*)d_in[13];
  const float* b_hh  = (const float*)d_in[14];
  const float* W_out = (const float*)d_in[15];
  const float* b_out = (const float*)d_in[16];

  char* ws = (char*)d_ws;
  __bf16* A0   = (__bf16*)(ws + OFF_A0);
  __bf16* A1   = (__bf16*)(ws + OFF_A1);
  __bf16* Alog = (__bf16*)(ws + OFF_ALOG);
  __bf16* Ah   = (__bf16*)(ws + OFF_AH);
  __bf16* Am   = (__bf16*)(ws + OFF_AM);
  __bf16* Al   = (__bf16*)(ws + OFF_AL);
  float* WaT   = (float*)(ws + OFF_WAT);
  float* q     = (float*)(ws + OFF_Q);
  float* z     = (float*)(ws + OFF_Z);
  float* p_t   = (float*)(ws + OFF_PT);
  int*   s_i   = (int*)  (ws + OFF_SI);
  float* sc    = (float*)(ws + OFF_SC);
  float* g0p   = (float*)(ws + OFF_G0P);
  float* g1p   = (float*)(ws + OFF_G1P);
  float* Pmax  = (float*)(ws + OFF_PMAX);
  float* Psum  = (float*)(ws + OFF_PSUM);

  float* out        = (float*)d_out;
  float* out_logits = out;
  float* out_h      = out + 4096000;
  float* out_c      = out + 4358144;
  float* out_ctx    = out + 4620288;
  float* out_s      = out + 4751360;

  // 1: transpose + prep (fused)
  k_prep_all<<<1152, 256, 0, stream>>>(W_a, WaT, ids, emb, h, b_pt, A0, Ah, Am, Al, z, q);
  // 2: q = h_top @ W_a (PREC2)  ||  z = h_top @ W_pt^T + b_pt (PREC3), one launch
  k_qz<<<dim3(16,4), 256, 0, stream>>>(Ah, Am, Al, WaT, W_pt, q, z);
  // 3: scores (+ fused p_t/s)
  k_scores<<<dim3(128,33), 256, 0, stream>>>(z, v_pt, b_v, q, h_s, b_a, sc, p_t, s_i, out_s);
  // 4: context (+ fused softmax*gauss), 2 blocks per batch element
  k_context<<<256, 256, 0, stream>>>(sc, s_i, p_t, h_s, h, out_ctx, A0, A1);
  // 5-6: layer 0 gates (K-split partial stores) + cell
  k_gemm<1,4><<<dim3(32,4), 256, 0, stream>>>(A0, nullptr, nullptr, 2048, W_ih, W_hh, 1024, 1024,
                                              nullptr, g0p, 4096, nullptr, nullptr);
  k_cell<<<512, 256, 0, stream>>>(g0p, b_ih, b_hh, c, out_h, out_c, A1, 2048);
  // 7-8: layer 1 gates + cell
  k_gemm<1,4><<<dim3(32,4), 256, 0, stream>>>(A1, nullptr, nullptr, 2048, W_ih + 4194304, W_hh + 4194304,
                                              1024, 1024, nullptr, g1p, 4096, nullptr, nullptr);
  k_cell<<<512, 256, 0, stream>>>(g1p, b_ih + 4096, b_hh + 4096, c + 131072,
                                  out_h + 131072, out_c + 131072, Alog, 1024);
  // 9: logits GEMM with fused log-softmax partials
  k_gemm<1,2><<<dim3(250,1), 256, 0, stream>>>(Alog, nullptr, nullptr, 1024, W_out, nullptr, 1024, 0,
                                               b_out, out_logits, 32000, Pmax, Psum);
  // 10: lse reduce + subtract (fused)
  k_lsesub<<<dim3(125,128), 64, 0, stream>>>(Pmax, Psum, out_logits);
}